// Round 10
// baseline (1138.203 us; speedup 1.0000x reference)
//
#include <hip/hip_runtime.h>

#define FEAT 128
#define RANGE 12800
#define NSLICE 64

typedef __attribute__((ext_vector_type(4))) float vf4;

// ---------- hist: src & dst partial histograms in one dispatch, ushort-packed ----------
__global__ __launch_bounds__(256) void hist_kernel(const int* __restrict__ src,
                                                   const int* __restrict__ dst,
                                                   unsigned* __restrict__ partialD,
                                                   unsigned* __restrict__ partialS,
                                                   int E, int NP) {
    __shared__ unsigned hpk[RANGE / 2];
    int per = (NP / RANGE) * NSLICE;
    int b = blockIdx.x;
    int halfsel = b / per;
    int q = b % per;
    int r = q / NSLICE;
    int s = q % NSLICE;
    const int* arr = halfsel ? src : dst;
    unsigned* out = halfsel ? partialS : partialD;
    int v0 = r * RANGE;
    int tid = threadIdx.x;
    for (int i = tid; i < RANGE / 2; i += 256) hpk[i] = 0;
    __syncthreads();
    int e0 = (int)((long long)E * s / NSLICE);
    int e1 = (int)((long long)E * (s + 1) / NSLICE);
    for (int e = e0 + tid; e < e1; e += 256) {
        unsigned d = (unsigned)(arr[e] - v0);
        if (d < RANGE) atomicAdd(&hpk[d >> 1], (d & 1) ? 65536u : 1u);
    }
    __syncthreads();
    size_t wbase = ((size_t)s * NP + v0) >> 1;
    for (int i = tid; i < RANGE / 2; i += 256) out[wbase + i] = hpk[i];
}

// ---------- scan phase 1: per-node slice-sums + norms ----------
__global__ __launch_bounds__(256) void scanp1_kernel(const unsigned short* __restrict__ pD,
                                                     const unsigned short* __restrict__ pS,
                                                     int* __restrict__ blockSums,
                                                     float* __restrict__ ns,
                                                     float* __restrict__ nd,
                                                     int NP, int n) {
    __shared__ int buf[256];
    int tid = threadIdx.x;
    int v = blockIdx.x * 256 + tid;
    int ssum = 0, osum = 0;
    #pragma unroll
    for (int s = 0; s < NSLICE; ++s) {
        ssum += pD[(size_t)s * NP + v];
        osum += pS[(size_t)s * NP + v];
    }
    if (v < n) {
        ns[v] = 1.0f / sqrtf((float)(osum < 1 ? 1 : osum));
        nd[v] = 1.0f / sqrtf((float)(ssum < 1 ? 1 : ssum));
    }
    buf[tid] = ssum;
    __syncthreads();
    #pragma unroll
    for (int off = 1; off < 256; off <<= 1) {
        int t = (tid >= off) ? buf[tid - off] : 0;
        __syncthreads();
        buf[tid] += t;
        __syncthreads();
    }
    if (tid == 255) blockSums[blockIdx.x] = buf[255];
}

// ---------- scan phase 2 ----------
__global__ __launch_bounds__(256) void scanp2_kernel(const int* __restrict__ blockSums,
                                                     int* __restrict__ blockOffs, int nb) {
    __shared__ int buf[256];
    int tid = threadIdx.x;
    int v = (tid < nb) ? blockSums[tid] : 0;
    buf[tid] = v;
    __syncthreads();
    #pragma unroll
    for (int off = 1; off < 256; off <<= 1) {
        int t = (tid >= off) ? buf[tid - off] : 0;
        __syncthreads();
        buf[tid] += t;
        __syncthreads();
    }
    if (tid < nb) blockOffs[tid] = buf[tid] - v;
}

// ---------- scan phase 3: per-(node,slice) cursors + compact offsets ----------
__global__ __launch_bounds__(256) void scanp3_kernel(const unsigned short* __restrict__ pD,
                                                     const int* __restrict__ blockOffs,
                                                     int* __restrict__ cursorV,
                                                     int* __restrict__ offsc,
                                                     int NP, int n) {
    __shared__ int buf[256];
    int tid = threadIdx.x;
    int v = blockIdx.x * 256 + tid;
    int ssum = 0;
    #pragma unroll
    for (int s = 0; s < NSLICE; ++s) ssum += pD[(size_t)s * NP + v];
    buf[tid] = ssum;
    __syncthreads();
    #pragma unroll
    for (int off = 1; off < 256; off <<= 1) {
        int t = (tid >= off) ? buf[tid - off] : 0;
        __syncthreads();
        buf[tid] += t;
        __syncthreads();
    }
    int o = blockOffs[blockIdx.x] + buf[tid] - ssum;
    if (v <= n) offsc[v] = o;
    int* cv = cursorV + (size_t)v * NSLICE;
    #pragma unroll
    for (int s = 0; s < NSLICE; ++s) {
        int val = pD[(size_t)s * NP + v];
        cv[s] = o;
        o += val;
    }
}

// ---------- prescale: xs = in_feat * ns (row-major) ----------
__global__ void prescale_kernel(const float* __restrict__ x, const float* __restrict__ ns,
                                float* __restrict__ xs, int n) {
    int i = blockIdx.x * blockDim.x + threadIdx.x;
    if (i >= n * (FEAT / 4)) return;
    int v = i >> 5;
    float w = ns[v];
    float4 t = ((const float4*)x)[i];
    t.x *= w; t.y *= w; t.z *= w; t.w *= w;
    ((float4*)xs)[i] = t;
}

// ---------- fill: place edges via LDS cursors ----------
__global__ __launch_bounds__(256) void fill_kernel(const int* __restrict__ src,
                                                   const int* __restrict__ dst,
                                                   const int* __restrict__ cursorV,
                                                   int* __restrict__ esrc, int E, int NP) {
    __shared__ int cur[RANGE];
    int b = blockIdx.x;
    int r = b / NSLICE;
    int inner = b % NSLICE;
    int s = ((inner & 7) << 3) | (inner >> 3);
    int v0 = r * RANGE;
    int tid = threadIdx.x;
    for (int i = tid; i < RANGE; i += 256)
        cur[i] = cursorV[(size_t)(v0 + i) * NSLICE + s];
    __syncthreads();
    int e0 = (int)((long long)E * s / NSLICE);
    int e1 = (int)((long long)E * (s + 1) / NSLICE);
    for (int e = e0 + tid; e < e1; e += 256) {
        unsigned dd = (unsigned)(dst[e] - v0);
        if (dd < RANGE) {
            int p = atomicAdd(&cur[dd], 1);
            esrc[p] = src[e];
        }
    }
}

// ---------- aggregation: R6 row-major form — one wave per node, half-wave float4 ----------
__global__ __launch_bounds__(256) void agg_kernel(const float* __restrict__ x,
                                                  const int* __restrict__ offs,
                                                  const int* __restrict__ esrc,
                                                  const float* __restrict__ nd,
                                                  float* __restrict__ m, int n) {
    int gid = blockIdx.x * blockDim.x + threadIdx.x;
    int v = gid >> 6;
    int lane = threadIdx.x & 63;
    int half = lane >> 5;
    int c = lane & 31;
    if (v >= n) return;
    int s0 = offs[v], s1 = offs[v + 1];
    float4 A0 = make_float4(0.f, 0.f, 0.f, 0.f);
    float4 A1 = make_float4(0.f, 0.f, 0.f, 0.f);
    float4 A2 = make_float4(0.f, 0.f, 0.f, 0.f);
    float4 A3 = make_float4(0.f, 0.f, 0.f, 0.f);
    int j = s0 + half;
    for (; j + 6 < s1; j += 8) {
        int e0 = esrc[j], e1 = esrc[j + 2], e2 = esrc[j + 4], e3 = esrc[j + 6];
        float4 t0 = ((const float4*)(x + (size_t)e0 * FEAT))[c];
        float4 t1 = ((const float4*)(x + (size_t)e1 * FEAT))[c];
        float4 t2 = ((const float4*)(x + (size_t)e2 * FEAT))[c];
        float4 t3 = ((const float4*)(x + (size_t)e3 * FEAT))[c];
        A0.x += t0.x; A0.y += t0.y; A0.z += t0.z; A0.w += t0.w;
        A1.x += t1.x; A1.y += t1.y; A1.z += t1.z; A1.w += t1.w;
        A2.x += t2.x; A2.y += t2.y; A2.z += t2.z; A2.w += t2.w;
        A3.x += t3.x; A3.y += t3.y; A3.z += t3.z; A3.w += t3.w;
    }
    for (; j < s1; j += 2) {
        int e0 = esrc[j];
        float4 t0 = ((const float4*)(x + (size_t)e0 * FEAT))[c];
        A0.x += t0.x; A0.y += t0.y; A0.z += t0.z; A0.w += t0.w;
    }
    A0.x += A1.x + A2.x + A3.x;
    A0.y += A1.y + A2.y + A3.y;
    A0.z += A1.z + A2.z + A3.z;
    A0.w += A1.w + A2.w + A3.w;
    A0.x += __shfl_xor(A0.x, 32);
    A0.y += __shfl_xor(A0.y, 32);
    A0.z += __shfl_xor(A0.z, 32);
    A0.w += __shfl_xor(A0.w, 32);
    if (half == 0) {
        float w = nd[v];
        float4 r;
        r.x = A0.x * w; r.y = A0.y * w; r.z = A0.z * w; r.w = A0.w * w;
        ((float4*)(m + (size_t)v * FEAT))[c] = r;
    }
}

// ---------- GEMM: 128x128 tile, 128 threads (2 waves), 8x16 acc, split blocking ----------
// rows {4ty..+3, 64+4ty..+3}, cols {8tx..+7, 64+8tx..+7} -> all LDS reads 2-way (free).
// Register double-buffer on both W and M chunk staging.
template<int MODE>   // 0: relu*ns epilogue   1: last layer (h in-place + threshold)
__global__ __launch_bounds__(128, 2) void gemm_kernel(const float* __restrict__ M,
                                                      const float* __restrict__ W,
                                                      const float* __restrict__ bias,
                                                      const float* __restrict__ nsv,
                                                      float* __restrict__ out,
                                                      float* __restrict__ out2, int n) {
    __shared__ float MsT[32][132];   // [k][row], 128 rows
    __shared__ float Ws[32][132];    // [k][col], 128 cols
    int tid = threadIdx.x;
    int tx = tid & 7;                // col base 8*tx
    int ty = tid >> 3;               // row base 4*ty  (ty 0..15)
    int r0 = blockIdx.x * 128;

    // staging indices: 1024 float4 per array, 8 per thread
    int wrow[8], wc4[8], mrow[8], mc4[8];
    #pragma unroll
    for (int i = 0; i < 8; ++i) {
        int idx = tid + i * 128;
        wrow[i] = idx >> 5; wc4[i] = idx & 31;      // W: 32 float4 per k-row
        mrow[i] = idx >> 3; mc4[i] = idx & 7;       // M: 8 float4 per node-row
    }

    float4 wr[8], mr[8];
    #pragma unroll
    for (int i = 0; i < 8; ++i)
        wr[i] = *(const float4*)(W + (size_t)wrow[i] * FEAT + wc4[i] * 4);
    #pragma unroll
    for (int i = 0; i < 8; ++i) {
        int gr = r0 + mrow[i];
        mr[i] = (gr < n) ? *(const float4*)(M + (size_t)gr * FEAT + mc4[i] * 4)
                         : make_float4(0.f, 0.f, 0.f, 0.f);
    }

    float acc[8][16];
    #pragma unroll
    for (int r = 0; r < 8; ++r)
        #pragma unroll
        for (int i = 0; i < 16; ++i) acc[r][i] = 0.f;

    for (int k0 = 0; k0 < FEAT; k0 += 32) {
        if (k0) __syncthreads();
        #pragma unroll
        for (int i = 0; i < 8; ++i)
            *(float4*)&Ws[wrow[i]][wc4[i] * 4] = wr[i];
        #pragma unroll
        for (int i = 0; i < 8; ++i) {
            MsT[mc4[i] * 4 + 0][mrow[i]] = mr[i].x;
            MsT[mc4[i] * 4 + 1][mrow[i]] = mr[i].y;
            MsT[mc4[i] * 4 + 2][mrow[i]] = mr[i].z;
            MsT[mc4[i] * 4 + 3][mrow[i]] = mr[i].w;
        }
        __syncthreads();
        int kn = k0 + 32;
        if (kn < FEAT) {
            #pragma unroll
            for (int i = 0; i < 8; ++i)
                wr[i] = *(const float4*)(W + (size_t)(kn + wrow[i]) * FEAT + wc4[i] * 4);
            #pragma unroll
            for (int i = 0; i < 8; ++i) {
                int gr = r0 + mrow[i];
                mr[i] = (gr < n) ? *(const float4*)(M + (size_t)gr * FEAT + kn + mc4[i] * 4)
                                 : make_float4(0.f, 0.f, 0.f, 0.f);
            }
        }
        #pragma unroll
        for (int kk = 0; kk < 32; ++kk) {
            float4 a0 = *(const float4*)&MsT[kk][ty * 4];
            float4 a1 = *(const float4*)&MsT[kk][64 + ty * 4];
            float4 w0 = *(const float4*)&Ws[kk][tx * 8];
            float4 w1 = *(const float4*)&Ws[kk][tx * 8 + 4];
            float4 w2 = *(const float4*)&Ws[kk][64 + tx * 8];
            float4 w3 = *(const float4*)&Ws[kk][64 + tx * 8 + 4];
            float a[8] = {a0.x, a0.y, a0.z, a0.w, a1.x, a1.y, a1.z, a1.w};
            float w[16] = {w0.x, w0.y, w0.z, w0.w, w1.x, w1.y, w1.z, w1.w,
                           w2.x, w2.y, w2.z, w2.w, w3.x, w3.y, w3.z, w3.w};
            #pragma unroll
            for (int r = 0; r < 8; ++r)
                #pragma unroll
                for (int i = 0; i < 16; ++i)
                    acc[r][i] = fmaf(a[r], w[i], acc[r][i]);
        }
    }

    float4 bv[4];
    bv[0] = *(const float4*)&bias[tx * 8];
    bv[1] = *(const float4*)&bias[tx * 8 + 4];
    bv[2] = *(const float4*)&bias[64 + tx * 8];
    bv[3] = *(const float4*)&bias[64 + tx * 8 + 4];
    #pragma unroll
    for (int rh = 0; rh < 2; ++rh) {
        #pragma unroll
        for (int rr = 0; rr < 4; ++rr) {
            int r = rh * 4 + rr;
            int row = r0 + rh * 64 + ty * 4 + rr;
            if (row >= n) continue;
            float sc_ = (MODE == 0) ? nsv[row] : 1.0f;
            #pragma unroll
            for (int cg = 0; cg < 4; ++cg) {
                int colbase = (cg >> 1) * 64 + tx * 8 + (cg & 1) * 4;
                float4 v;
                v.x = acc[r][cg * 4 + 0] + ((const float*)&bv[cg])[0];
                v.y = acc[r][cg * 4 + 1] + ((const float*)&bv[cg])[1];
                v.z = acc[r][cg * 4 + 2] + ((const float*)&bv[cg])[2];
                v.w = acc[r][cg * 4 + 3] + ((const float*)&bv[cg])[3];
                v.x = v.x > 0.f ? v.x : 0.f; v.y = v.y > 0.f ? v.y : 0.f;
                v.z = v.z > 0.f ? v.z : 0.f; v.w = v.w > 0.f ? v.w : 0.f;
                if (MODE == 0) {
                    v.x *= sc_; v.y *= sc_; v.z *= sc_; v.w *= sc_;
                    *(float4*)(out + (size_t)row * FEAT + colbase) = v;
                } else {
                    *(float4*)(out + (size_t)row * FEAT + colbase) = v;
                    float4 cth;
                    cth.x = v.x >= 0.5f ? 1.f : 0.f;
                    cth.y = v.y >= 0.5f ? 1.f : 0.f;
                    cth.z = v.z >= 0.5f ? 1.f : 0.f;
                    cth.w = v.w >= 0.5f ? 1.f : 0.f;
                    *(float4*)(out2 + (size_t)row * FEAT + colbase) = cth;
                }
            }
        }
    }
}

extern "C" void kernel_launch(void* const* d_in, const int* in_sizes, int n_in,
                              void* d_out, int out_size, void* d_ws, size_t ws_size,
                              hipStream_t stream) {
    const float* in_feat = (const float*)d_in[0];
    const int*   src     = (const int*)d_in[1];
    const int*   dst     = (const int*)d_in[2];
    const float* W[5] = {(const float*)d_in[3], (const float*)d_in[5], (const float*)d_in[7],
                         (const float*)d_in[9], (const float*)d_in[11]};
    const float* B[5] = {(const float*)d_in[4], (const float*)d_in[6], (const float*)d_in[8],
                         (const float*)d_in[10], (const float*)d_in[12]};
    const int E = in_sizes[1];
    const int N = in_sizes[0] / FEAT;
    const int NRANGE = (N + RANGE - 1) / RANGE;
    const int NP = NRANGE * RANGE;
    const size_t MTOT = (size_t)NP * NSLICE;

    char* ws = (char*)d_ws;
    size_t off = 0;
    auto alloc = [&](size_t bytes) { size_t o = off; off += (bytes + 255) & ~size_t(255); return o; };
    unsigned* partialD = (unsigned*)(ws + alloc(MTOT * 2));
    size_t    pS_off   = alloc(MTOT * 2);
    unsigned* partialS = (unsigned*)(ws + pS_off);
    int*      esrc     = (int*)(ws + pS_off);          // aliases partialS (dead after scanp1)
    int*      cursorV  = (int*)(ws + alloc(MTOT * 4));
    float*    ns       = (float*)(ws + alloc((size_t)N * 4));
    float*    nd       = (float*)(ws + alloc((size_t)N * 4));
    int*      offsc    = (int*)(ws + alloc((size_t)(N + 1) * 4));
    int*      blockSums = (int*)(ws + alloc(1024));
    int*      blockOffs = (int*)(ws + alloc(1024));

    float* out_h = (float*)d_out;              // m scratch; h5 at the end (in-place gemm5)
    float* out_c = out_h + (size_t)N * FEAT;   // scaled-x chain; threshold at the end

    const int histBlocks = 2 * NRANGE * NSLICE;
    const int scanBlocks = NP / 256;
    hist_kernel<<<histBlocks, 256, 0, stream>>>(src, dst, partialD, partialS, E, NP);
    scanp1_kernel<<<scanBlocks, 256, 0, stream>>>((const unsigned short*)partialD,
                                                  (const unsigned short*)partialS,
                                                  blockSums, ns, nd, NP, N);
    scanp2_kernel<<<1, 256, 0, stream>>>(blockSums, blockOffs, scanBlocks);
    scanp3_kernel<<<scanBlocks, 256, 0, stream>>>((const unsigned short*)partialD,
                                                  blockOffs, cursorV, offsc, NP, N);
    prescale_kernel<<<(N * 32 + 255) / 256, 256, 0, stream>>>(in_feat, ns, out_c, N);
    fill_kernel<<<NRANGE * NSLICE, 256, 0, stream>>>(src, dst, cursorV, esrc, E, NP);

    const int agg_blocks = (int)(((size_t)N * 64 + 255) / 256);
    const int gemm_blocks = (N + 127) / 128;

    for (int l = 0; l < 5; ++l) {
        agg_kernel<<<agg_blocks, 256, 0, stream>>>(out_c, offsc, esrc, nd, out_h, N);
        if (l < 4)
            gemm_kernel<0><<<gemm_blocks, 128, 0, stream>>>(out_h, W[l], B[l], ns, out_c, nullptr, N);
        else
            gemm_kernel<1><<<gemm_blocks, 128, 0, stream>>>(out_h, W[l], B[l], ns, out_h, out_c, N);
    }
}

// Round 11
// 608.112 us; speedup vs baseline: 1.8717x; 1.8717x over previous
//
#include <hip/hip_runtime.h>

#define FEAT 128
#define RANGE 12800
#define NSLICE 64

typedef unsigned int u32;
// async global->LDS copy, 16B per lane; lds dest = uniform base + lane*16
#define GLD16(g, l) __builtin_amdgcn_global_load_lds( \
    (const __attribute__((address_space(1))) u32*)(g), \
    (__attribute__((address_space(3))) u32*)(l), 16, 0, 0)

// ---------- hist: src & dst partial histograms in one dispatch, ushort-packed ----------
__global__ __launch_bounds__(256) void hist_kernel(const int* __restrict__ src,
                                                   const int* __restrict__ dst,
                                                   unsigned* __restrict__ partialD,
                                                   unsigned* __restrict__ partialS,
                                                   int E, int NP) {
    __shared__ unsigned hpk[RANGE / 2];
    int per = (NP / RANGE) * NSLICE;
    int b = blockIdx.x;
    int halfsel = b / per;
    int q = b % per;
    int r = q / NSLICE;
    int s = q % NSLICE;
    const int* arr = halfsel ? src : dst;
    unsigned* out = halfsel ? partialS : partialD;
    int v0 = r * RANGE;
    int tid = threadIdx.x;
    for (int i = tid; i < RANGE / 2; i += 256) hpk[i] = 0;
    __syncthreads();
    int e0 = (int)((long long)E * s / NSLICE);
    int e1 = (int)((long long)E * (s + 1) / NSLICE);
    for (int e = e0 + tid; e < e1; e += 256) {
        unsigned d = (unsigned)(arr[e] - v0);
        if (d < RANGE) atomicAdd(&hpk[d >> 1], (d & 1) ? 65536u : 1u);
    }
    __syncthreads();
    size_t wbase = ((size_t)s * NP + v0) >> 1;
    for (int i = tid; i < RANGE / 2; i += 256) out[wbase + i] = hpk[i];
}

// ---------- scan phase 1: per-node slice-sums + norms ----------
__global__ __launch_bounds__(256) void scanp1_kernel(const unsigned short* __restrict__ pD,
                                                     const unsigned short* __restrict__ pS,
                                                     int* __restrict__ blockSums,
                                                     float* __restrict__ ns,
                                                     float* __restrict__ nd,
                                                     int NP, int n) {
    __shared__ int buf[256];
    int tid = threadIdx.x;
    int v = blockIdx.x * 256 + tid;
    int ssum = 0, osum = 0;
    #pragma unroll
    for (int s = 0; s < NSLICE; ++s) {
        ssum += pD[(size_t)s * NP + v];
        osum += pS[(size_t)s * NP + v];
    }
    if (v < n) {
        ns[v] = 1.0f / sqrtf((float)(osum < 1 ? 1 : osum));
        nd[v] = 1.0f / sqrtf((float)(ssum < 1 ? 1 : ssum));
    }
    buf[tid] = ssum;
    __syncthreads();
    #pragma unroll
    for (int off = 1; off < 256; off <<= 1) {
        int t = (tid >= off) ? buf[tid - off] : 0;
        __syncthreads();
        buf[tid] += t;
        __syncthreads();
    }
    if (tid == 255) blockSums[blockIdx.x] = buf[255];
}

// ---------- scan phase 2 ----------
__global__ __launch_bounds__(256) void scanp2_kernel(const int* __restrict__ blockSums,
                                                     int* __restrict__ blockOffs, int nb) {
    __shared__ int buf[256];
    int tid = threadIdx.x;
    int v = (tid < nb) ? blockSums[tid] : 0;
    buf[tid] = v;
    __syncthreads();
    #pragma unroll
    for (int off = 1; off < 256; off <<= 1) {
        int t = (tid >= off) ? buf[tid - off] : 0;
        __syncthreads();
        buf[tid] += t;
        __syncthreads();
    }
    if (tid < nb) blockOffs[tid] = buf[tid] - v;
}

// ---------- scan phase 3: per-(node,slice) cursors + compact offsets ----------
__global__ __launch_bounds__(256) void scanp3_kernel(const unsigned short* __restrict__ pD,
                                                     const int* __restrict__ blockOffs,
                                                     int* __restrict__ cursorV,
                                                     int* __restrict__ offsc,
                                                     int NP, int n) {
    __shared__ int buf[256];
    int tid = threadIdx.x;
    int v = blockIdx.x * 256 + tid;
    int ssum = 0;
    #pragma unroll
    for (int s = 0; s < NSLICE; ++s) ssum += pD[(size_t)s * NP + v];
    buf[tid] = ssum;
    __syncthreads();
    #pragma unroll
    for (int off = 1; off < 256; off <<= 1) {
        int t = (tid >= off) ? buf[tid - off] : 0;
        __syncthreads();
        buf[tid] += t;
        __syncthreads();
    }
    int o = blockOffs[blockIdx.x] + buf[tid] - ssum;
    if (v <= n) offsc[v] = o;
    int* cv = cursorV + (size_t)v * NSLICE;
    #pragma unroll
    for (int s = 0; s < NSLICE; ++s) {
        int val = pD[(size_t)s * NP + v];
        cv[s] = o;
        o += val;
    }
}

// ---------- prescale: xs = in_feat * ns (row-major) ----------
__global__ void prescale_kernel(const float* __restrict__ x, const float* __restrict__ ns,
                                float* __restrict__ xs, int n) {
    int i = blockIdx.x * blockDim.x + threadIdx.x;
    if (i >= n * (FEAT / 4)) return;
    int v = i >> 5;
    float w = ns[v];
    float4 t = ((const float4*)x)[i];
    t.x *= w; t.y *= w; t.z *= w; t.w *= w;
    ((float4*)xs)[i] = t;
}

// ---------- fill: place edges via LDS cursors ----------
__global__ __launch_bounds__(256) void fill_kernel(const int* __restrict__ src,
                                                   const int* __restrict__ dst,
                                                   const int* __restrict__ cursorV,
                                                   int* __restrict__ esrc, int E, int NP) {
    __shared__ int cur[RANGE];
    int b = blockIdx.x;
    int r = b / NSLICE;
    int inner = b % NSLICE;
    int s = ((inner & 7) << 3) | (inner >> 3);
    int v0 = r * RANGE;
    int tid = threadIdx.x;
    for (int i = tid; i < RANGE; i += 256)
        cur[i] = cursorV[(size_t)(v0 + i) * NSLICE + s];
    __syncthreads();
    int e0 = (int)((long long)E * s / NSLICE);
    int e1 = (int)((long long)E * (s + 1) / NSLICE);
    for (int e = e0 + tid; e < e1; e += 256) {
        unsigned dd = (unsigned)(dst[e] - v0);
        if (dd < RANGE) {
            int p = atomicAdd(&cur[dd], 1);
            esrc[p] = src[e];
        }
    }
}

// ---------- aggregation: one wave per node, half-wave float4, 8 rows in flight ----------
__global__ __launch_bounds__(256) void agg_kernel(const float* __restrict__ x,
                                                  const int* __restrict__ offs,
                                                  const int* __restrict__ esrc,
                                                  const float* __restrict__ nd,
                                                  float* __restrict__ m, int n) {
    int gid = blockIdx.x * blockDim.x + threadIdx.x;
    int v = gid >> 6;
    int lane = threadIdx.x & 63;
    int half = lane >> 5;
    int c = lane & 31;
    if (v >= n) return;
    int s0 = offs[v], s1 = offs[v + 1];
    float4 A0 = make_float4(0.f, 0.f, 0.f, 0.f);
    float4 A1 = make_float4(0.f, 0.f, 0.f, 0.f);
    float4 A2 = make_float4(0.f, 0.f, 0.f, 0.f);
    float4 A3 = make_float4(0.f, 0.f, 0.f, 0.f);
    int j = s0 + half;
    for (; j + 6 < s1; j += 8) {
        int e0 = __builtin_nontemporal_load(esrc + j);
        int e1 = __builtin_nontemporal_load(esrc + j + 2);
        int e2 = __builtin_nontemporal_load(esrc + j + 4);
        int e3 = __builtin_nontemporal_load(esrc + j + 6);
        float4 t0 = ((const float4*)(x + (size_t)e0 * FEAT))[c];
        float4 t1 = ((const float4*)(x + (size_t)e1 * FEAT))[c];
        float4 t2 = ((const float4*)(x + (size_t)e2 * FEAT))[c];
        float4 t3 = ((const float4*)(x + (size_t)e3 * FEAT))[c];
        A0.x += t0.x; A0.y += t0.y; A0.z += t0.z; A0.w += t0.w;
        A1.x += t1.x; A1.y += t1.y; A1.z += t1.z; A1.w += t1.w;
        A2.x += t2.x; A2.y += t2.y; A2.z += t2.z; A2.w += t2.w;
        A3.x += t3.x; A3.y += t3.y; A3.z += t3.z; A3.w += t3.w;
    }
    for (; j < s1; j += 2) {
        int e0 = __builtin_nontemporal_load(esrc + j);
        float4 t0 = ((const float4*)(x + (size_t)e0 * FEAT))[c];
        A0.x += t0.x; A0.y += t0.y; A0.z += t0.z; A0.w += t0.w;
    }
    A0.x += A1.x + A2.x + A3.x;
    A0.y += A1.y + A2.y + A3.y;
    A0.z += A1.z + A2.z + A3.z;
    A0.w += A1.w + A2.w + A3.w;
    A0.x += __shfl_xor(A0.x, 32);
    A0.y += __shfl_xor(A0.y, 32);
    A0.z += __shfl_xor(A0.z, 32);
    A0.w += __shfl_xor(A0.w, 32);
    if (half == 0) {
        float w = nd[v];
        float4 r;
        r.x = A0.x * w; r.y = A0.y * w; r.z = A0.z * w; r.w = A0.w * w;
        ((float4*)(m + (size_t)v * FEAT))[c] = r;
    }
}

// ---------- GEMM: 64x128 tile, 256 threads (4 waves), 4x8 blocking ----------
// W chunk staged via async global_load_lds (contiguous 16KB, byte-identical layout);
// M tile transposed via VGPRs (overlaps with the async W fetch).
template<int MODE>   // 0: relu*ns epilogue   1: last layer (h in-place + threshold)
__global__ __launch_bounds__(256) void gemm_kernel(const float* __restrict__ M,
                                                   const float* __restrict__ W,
                                                   const float* __restrict__ bias,
                                                   const float* __restrict__ nsv,
                                                   float* __restrict__ out,
                                                   float* __restrict__ out2, int n) {
    __shared__ float MsT[32][68];    // [k][row] transposed, stride 68 (16B-aligned)
    __shared__ float Ws[32][128];    // byte-identical to W chunk
    __shared__ float ns_s[64];
    int tid = threadIdx.x;
    int tx = tid & 15;     // cols tx*4..+3 and 64+tx*4..+3
    int ty = tid >> 4;     // rows ty*4..+3
    int lane = tid & 63;
    int wave = tid >> 6;
    int r0 = blockIdx.x * 64;
    if (MODE == 0 && tid < 64) ns_s[tid] = (r0 + tid < n) ? nsv[r0 + tid] : 1.0f;

    float acc[4][8];
    #pragma unroll
    for (int r = 0; r < 4; ++r)
        #pragma unroll
        for (int i = 0; i < 8; ++i) acc[r][i] = 0.f;

    // per-wave staging geometry for W: wave w copies bytes [w*4096, (w+1)*4096)
    char* wsBase = (char*)&Ws[0][0] + wave * 4096 + lane * 16;

    for (int k0 = 0; k0 < FEAT; k0 += 32) {
        if (k0) __syncthreads();
        // async W chunk: 16 KB contiguous, 4 calls per wave (1 KB each)
        const char* wg = (const char*)(W + (size_t)k0 * FEAT) + wave * 4096 + lane * 16;
        #pragma unroll
        for (int i = 0; i < 4; ++i)
            GLD16(wg + i * 1024, wsBase + i * 1024);
        // M tile transposed: 512 float4, 2 per thread (VGPR path, overlaps async W)
        #pragma unroll
        for (int jj = 0; jj < 2; ++jj) {
            int i = tid + jj * 256;
            int row = i >> 3, c4 = i & 7;
            int gr = r0 + row;
            float4 v = make_float4(0.f, 0.f, 0.f, 0.f);
            if (gr < n) v = *(const float4*)(M + (size_t)gr * FEAT + k0 + c4 * 4);
            MsT[c4 * 4 + 0][row] = v.x;
            MsT[c4 * 4 + 1][row] = v.y;
            MsT[c4 * 4 + 2][row] = v.z;
            MsT[c4 * 4 + 3][row] = v.w;
        }
        __syncthreads();
        #pragma unroll
        for (int kk = 0; kk < 32; ++kk) {
            float4 a4 = *(const float4*)&MsT[kk][ty * 4];
            float4 w0 = *(const float4*)&Ws[kk][tx * 4];
            float4 w1 = *(const float4*)&Ws[kk][64 + tx * 4];
            float a[4] = {a4.x, a4.y, a4.z, a4.w};
            float w[8] = {w0.x, w0.y, w0.z, w0.w, w1.x, w1.y, w1.z, w1.w};
            #pragma unroll
            for (int r = 0; r < 4; ++r)
                #pragma unroll
                for (int i = 0; i < 8; ++i)
                    acc[r][i] = fmaf(a[r], w[i], acc[r][i]);
        }
    }

    float4 b0 = *(const float4*)&bias[tx * 4];
    float4 b1 = *(const float4*)&bias[64 + tx * 4];
    #pragma unroll
    for (int r = 0; r < 4; ++r) {
        int row = r0 + ty * 4 + r;
        if (row < n) {
            float4 v0, v1;
            v0.x = acc[r][0] + b0.x; v0.y = acc[r][1] + b0.y;
            v0.z = acc[r][2] + b0.z; v0.w = acc[r][3] + b0.w;
            v1.x = acc[r][4] + b1.x; v1.y = acc[r][5] + b1.y;
            v1.z = acc[r][6] + b1.z; v1.w = acc[r][7] + b1.w;
            v0.x = v0.x > 0.f ? v0.x : 0.f; v0.y = v0.y > 0.f ? v0.y : 0.f;
            v0.z = v0.z > 0.f ? v0.z : 0.f; v0.w = v0.w > 0.f ? v0.w : 0.f;
            v1.x = v1.x > 0.f ? v1.x : 0.f; v1.y = v1.y > 0.f ? v1.y : 0.f;
            v1.z = v1.z > 0.f ? v1.z : 0.f; v1.w = v1.w > 0.f ? v1.w : 0.f;
            if (MODE == 0) {
                float sc_ = ns_s[ty * 4 + r];
                v0.x *= sc_; v0.y *= sc_; v0.z *= sc_; v0.w *= sc_;
                v1.x *= sc_; v1.y *= sc_; v1.z *= sc_; v1.w *= sc_;
            }
            *(float4*)(out + (size_t)row * FEAT + tx * 4) = v0;
            *(float4*)(out + (size_t)row * FEAT + 64 + tx * 4) = v1;
            if (MODE == 1) {
                float4 c0, c1;
                c0.x = v0.x >= 0.5f ? 1.f : 0.f; c0.y = v0.y >= 0.5f ? 1.f : 0.f;
                c0.z = v0.z >= 0.5f ? 1.f : 0.f; c0.w = v0.w >= 0.5f ? 1.f : 0.f;
                c1.x = v1.x >= 0.5f ? 1.f : 0.f; c1.y = v1.y >= 0.5f ? 1.f : 0.f;
                c1.z = v1.z >= 0.5f ? 1.f : 0.f; c1.w = v1.w >= 0.5f ? 1.f : 0.f;
                *(float4*)(out2 + (size_t)row * FEAT + tx * 4) = c0;
                *(float4*)(out2 + (size_t)row * FEAT + 64 + tx * 4) = c1;
            }
        }
    }
}

extern "C" void kernel_launch(void* const* d_in, const int* in_sizes, int n_in,
                              void* d_out, int out_size, void* d_ws, size_t ws_size,
                              hipStream_t stream) {
    const float* in_feat = (const float*)d_in[0];
    const int*   src     = (const int*)d_in[1];
    const int*   dst     = (const int*)d_in[2];
    const float* W[5] = {(const float*)d_in[3], (const float*)d_in[5], (const float*)d_in[7],
                         (const float*)d_in[9], (const float*)d_in[11]};
    const float* B[5] = {(const float*)d_in[4], (const float*)d_in[6], (const float*)d_in[8],
                         (const float*)d_in[10], (const float*)d_in[12]};
    const int E = in_sizes[1];
    const int N = in_sizes[0] / FEAT;
    const int NRANGE = (N + RANGE - 1) / RANGE;
    const int NP = NRANGE * RANGE;
    const size_t MTOT = (size_t)NP * NSLICE;

    char* ws = (char*)d_ws;
    size_t off = 0;
    auto alloc = [&](size_t bytes) { size_t o = off; off += (bytes + 255) & ~size_t(255); return o; };
    unsigned* partialD = (unsigned*)(ws + alloc(MTOT * 2));
    size_t    pS_off   = alloc(MTOT * 2);
    unsigned* partialS = (unsigned*)(ws + pS_off);
    int*      esrc     = (int*)(ws + pS_off);          // aliases partialS (dead after scanp1)
    int*      cursorV  = (int*)(ws + alloc(MTOT * 4));
    float*    ns       = (float*)(ws + alloc((size_t)N * 4));
    float*    nd       = (float*)(ws + alloc((size_t)N * 4));
    int*      offsc    = (int*)(ws + alloc((size_t)(N + 1) * 4));
    int*      blockSums = (int*)(ws + alloc(1024));
    int*      blockOffs = (int*)(ws + alloc(1024));

    float* out_h = (float*)d_out;              // m scratch; h5 at the end (in-place gemm5)
    float* out_c = out_h + (size_t)N * FEAT;   // scaled-x chain; threshold at the end

    const int histBlocks = 2 * NRANGE * NSLICE;
    const int scanBlocks = NP / 256;
    hist_kernel<<<histBlocks, 256, 0, stream>>>(src, dst, partialD, partialS, E, NP);
    scanp1_kernel<<<scanBlocks, 256, 0, stream>>>((const unsigned short*)partialD,
                                                  (const unsigned short*)partialS,
                                                  blockSums, ns, nd, NP, N);
    scanp2_kernel<<<1, 256, 0, stream>>>(blockSums, blockOffs, scanBlocks);
    scanp3_kernel<<<scanBlocks, 256, 0, stream>>>((const unsigned short*)partialD,
                                                  blockOffs, cursorV, offsc, NP, N);
    prescale_kernel<<<(N * 32 + 255) / 256, 256, 0, stream>>>(in_feat, ns, out_c, N);
    fill_kernel<<<NRANGE * NSLICE, 256, 0, stream>>>(src, dst, cursorV, esrc, E, NP);

    const int agg_blocks = (int)(((size_t)N * 64 + 255) / 256);
    const int gemm_blocks = (N + 63) / 64;

    for (int l = 0; l < 5; ++l) {
        agg_kernel<<<agg_blocks, 256, 0, stream>>>(out_c, offsc, esrc, nd, out_h, N);
        if (l < 4)
            gemm_kernel<0><<<gemm_blocks, 256, 0, stream>>>(out_h, W[l], B[l], ns, out_c, nullptr, N);
        else
            gemm_kernel<1><<<gemm_blocks, 256, 0, stream>>>(out_h, W[l], B[l], ns, out_h, out_c, N);
    }
}